// Round 4
// baseline (3734.562 us; speedup 1.0000x reference)
//
#include <hip/hip_runtime.h>
#include <stdint.h>

// LSTM: B=256, T=512, D=128, H=512, C=10
// R13 = R12's LDS-shared broadcast + R10's "data IS the flag", + LDS swizzle.
// R12 post-mortem: 4.19e7 LDS bank conflicts (half-wave hit 16/32 banks) and
// a serial chain of [drain->flag->propagate->poll->separate h-load]. Fix:
// (1) LDS index kc*256 + q*64 + col*4 -> all 32 banks covered 4x per 32
//     lanes (b128 minimum, conflict-free).
// (2) Delete flags. Consumers poll the h DATA directly (wave w polls its
//     64B/lane quarter from exactly 2 producer blocks); the successful
//     iteration already holds the MFMA operands. 4-slot rotation; each lane
//     sentinel-resets its OWN publish addr in slot (t+2)%4 at loop top
//     (safe: having validated h(t-1) proves all waves finished step t-2's
//     reads of that slot). Reset is drained by the pre-publish vmcnt(0),
//     so it is MALL-visible before the h(t+1) that gates consumers from
//     reaching that slot. Sentinel 0x7F7F7F7F7F7F7F7F is unreachable
//     (|h|<=1 => f16 in [0,0x3C00]|[0x8000,0xBC00]); 8B stores atomic.
// (3) LDS double-buffer -> ONE __syncthreads per step (write->read only;
//     cross-step reuse safe because barrier(t) proves step t-1 reads done).
// Spec-load for step t+1 issued right after publish -> poll usually short.

#define T_STEPS 512
#define BATCH   256
#define DIM     128
#define HID     512
#define NGRP    16
#define BT      16
#define RBUF    4

typedef _Float16 half8 __attribute__((ext_vector_type(8)));
typedef _Float16 half4 __attribute__((ext_vector_type(4)));
typedef float    f32x4 __attribute__((ext_vector_type(4)));
typedef unsigned u32x4 __attribute__((ext_vector_type(4)));

#define SLOT_HALFS (BATCH * HID)
#define SLOT_U64   (SLOT_HALFS / 4)
#define WS_NEEDED  (RBUF * SLOT_HALFS * 2)       // 1 MiB
#define SENT       0x7F7F7F7F7F7F7F7FULL

__device__ __forceinline__ half8 cvt8(f32x4 a, f32x4 b) {
  half8 r;
  r[0]=(_Float16)a[0]; r[1]=(_Float16)a[1]; r[2]=(_Float16)a[2]; r[3]=(_Float16)a[3];
  r[4]=(_Float16)b[0]; r[5]=(_Float16)b[1]; r[6]=(_Float16)b[2]; r[7]=(_Float16)b[3];
  return r;
}
__device__ __forceinline__ half8 load8_cvt(const float* p) {
  const f32x4* q = (const f32x4*)p;
  return cvt8(q[0], q[1]);
}
__device__ __forceinline__ float fsig(float x) {
  return __builtin_amdgcn_rcpf(1.f + __expf(-x));
}
__device__ __forceinline__ float ftanh(float x) {
  return 1.f - 2.f * __builtin_amdgcn_rcpf(1.f + __expf(2.f * x));
}

union h4u { unsigned long long u; half4 h; };
union c16 { unsigned long long u2[2]; u32x4 v; };

__global__ __launch_bounds__(256, 1) void lstm_persistent(
    const float* __restrict__ X,   const float* __restrict__ Wih,
    const float* __restrict__ Whh, const float* __restrict__ bih,
    const float* __restrict__ bhh, const float* __restrict__ Wlin,
    float* __restrict__ out, _Float16* __restrict__ hbuf)
{
  // double-buffered 16KB h-share; u32 idx = kc*256 + q*64 + col*4
  // (32 consecutive lanes cover all 32 banks exactly 4x -> conflict-free)
  __shared__ unsigned hsh[2][4096];

  const int tid  = threadIdx.x;
  const int w    = tid >> 6;
  const int lane = tid & 63;
  const int col  = lane & 15;        // batch-within-group; W A-frag row
  const int q    = lane >> 4;        // 0..3
  const int bid  = blockIdx.x;
  const int g    = bid & 15;         // group
  const int blk  = bid >> 4;         // 0..7 within group
  const int J    = blk * 64 + w * 16;   // hidden-unit base owned by this wave
  const int b_my = g * BT + col;     // this lane's batch

  // ---- W fragments into registers (once) ----
  half8 whh[16][4];                  // [k-chunk of 32][gate]
  half8 wih[4][4];
  #pragma unroll
  for (int kc = 0; kc < 16; ++kc)
    #pragma unroll
    for (int mt = 0; mt < 4; ++mt) {
      const int row = mt * HID + J + col;
      whh[kc][mt] = load8_cvt(Whh + (size_t)row * HID + kc * 32 + q * 8);
    }
  #pragma unroll
  for (int xc = 0; xc < 4; ++xc)
    #pragma unroll
    for (int mt = 0; mt < 4; ++mt) {
      const int row = mt * HID + J + col;
      wih[xc][mt] = load8_cvt(Wih + (size_t)row * DIM + xc * 32 + q * 8);
    }

  float bias[4][4], c_st[4], hsum[4];
  #pragma unroll
  for (int mt = 0; mt < 4; ++mt)
    #pragma unroll
    for (int r = 0; r < 4; ++r) {
      const int row = mt * HID + J + q * 4 + r;
      bias[mt][r] = bih[row] + bhh[row];
    }
  #pragma unroll
  for (int r = 0; r < 4; ++r) { c_st[r] = 0.f; hsum[r] = 0.f; }

  const float* Xb = X + (size_t)b_my * T_STEPS * DIM;
  unsigned long long* h64 = (unsigned long long*)hbuf;
  const size_t pub_u64 = ((size_t)b_my * HID + J + q * 4) >> 2;  // own 8B publish slot
  const size_t con_u64 = (((size_t)b_my * HID) >> 2) + q * 2;    // consumer chunk base

  // ---- prologue: acc = xp(0); prefetch X(1)->xr1, X(2)->xr0 ----
  f32x4 xr0[8], xr1[8];                // buf[k&1] holds X(k)
  #pragma unroll
  for (int xc = 0; xc < 4; ++xc) {
    const f32x4* p = (const f32x4*)(Xb + xc * 32 + q * 8);
    xr0[2 * xc] = p[0]; xr0[2 * xc + 1] = p[1];
  }
  f32x4 acc[4];
  #pragma unroll
  for (int mt = 0; mt < 4; ++mt) acc[mt] = (f32x4){0.f, 0.f, 0.f, 0.f};
  #pragma unroll
  for (int xc = 0; xc < 4; ++xc) {
    half8 xb = cvt8(xr0[2 * xc], xr0[2 * xc + 1]);
    #pragma unroll
    for (int mt = 0; mt < 4; ++mt)
      acc[mt] = __builtin_amdgcn_mfma_f32_16x16x32_f16(wih[xc][mt], xb, acc[mt], 0, 0, 0);
  }
  #pragma unroll
  for (int xc = 0; xc < 4; ++xc) {
    const f32x4* p1 = (const f32x4*)(Xb + (size_t)1 * DIM + xc * 32 + q * 8);
    const f32x4* p2 = (const f32x4*)(Xb + (size_t)2 * DIM + xc * 32 + q * 8);
    xr1[2 * xc] = p1[0]; xr1[2 * xc + 1] = p1[1];
    xr0[2 * xc] = p2[0]; xr0[2 * xc + 1] = p2[1];
  }

  // speculative h-chunk registers (this wave's quarter: kc in [4w,4w+4))
  unsigned long long lo[4], hi[4];
  #pragma unroll
  for (int i = 0; i < 4; ++i) { lo[i] = SENT; hi[i] = SENT; }

  for (int t = 0; t < T_STEPS; ++t) {
    // sentinel-reset own publish addr in slot (t+2)%4 (holds h(t-2); having
    // validated h(t-1) last step proves every wave finished its step-(t-2)
    // reads). Drained by this step's pre-publish vmcnt(0) -> visible before
    // h(t+1), which gates any consumer from polling that slot.
    __hip_atomic_store(h64 + (size_t)((t + 2) & 3) * SLOT_U64 + pub_u64,
                       (unsigned long long)SENT, __ATOMIC_RELAXED,
                       __HIP_MEMORY_SCOPE_AGENT);

    if (t > 0) {
      // poll the data itself: spec values first, reload on miss
      const unsigned long long* hp = h64 + (size_t)(t & 3) * SLOT_U64 + con_u64;
      for (;;) {
        int ok = 1;
        #pragma unroll
        for (int i = 0; i < 4; ++i)
          ok &= (int)(lo[i] != SENT) & (int)(hi[i] != SENT);
        if (__all(ok)) break;
        #pragma unroll
        for (int i = 0; i < 4; ++i) {
          const int kc = w * 4 + i;
          lo[i] = __hip_atomic_load(hp + kc * 8,     __ATOMIC_RELAXED, __HIP_MEMORY_SCOPE_AGENT);
          hi[i] = __hip_atomic_load(hp + kc * 8 + 1, __ATOMIC_RELAXED, __HIP_MEMORY_SCOPE_AGENT);
        }
      }
      __builtin_amdgcn_sched_barrier(0);  // nothing crosses the spin

      // stage quarter to LDS (swizzled, conflict-free)
      #pragma unroll
      for (int i = 0; i < 4; ++i) {
        const int kc = w * 4 + i;
        c16 u; u.u2[0] = lo[i]; u.u2[1] = hi[i];
        *(u32x4*)(&hsh[t & 1][kc * 256 + q * 64 + col * 4]) = u.v;
      }
      __syncthreads();   // the ONE barrier: write->read (cross-step safe
                         // via double buffer + barrier-implied progress)

      // full h(t) from LDS -> MFMA
      #pragma unroll
      for (int kc = 0; kc < 16; ++kc) {
        const half8 hbv = *(const half8*)(&hsh[t & 1][kc * 256 + q * 64 + col * 4]);
        #pragma unroll
        for (int mt = 0; mt < 4; ++mt)
          acc[mt] = __builtin_amdgcn_mfma_f32_16x16x32_f16(whh[kc][mt], hbv, acc[mt], 0, 0, 0);
      }
    }

    // gates -> c,h ; each lane owns units J+q*4..+3 for batch col
    h4u hv;
    #pragma unroll
    for (int r = 0; r < 4; ++r) {
      const float ig = fsig(acc[0][r] + bias[0][r]);
      const float fg = fsig(acc[1][r] + bias[1][r]);
      const float gg = ftanh(acc[2][r] + bias[2][r]);
      const float og = fsig(acc[3][r] + bias[3][r]);
      const float cc = fg * c_st[r] + ig * gg;
      c_st[r] = cc;
      const float h = og * ftanh(cc);
      hsum[r] += h;
      hv.h[r] = (_Float16)h;
    }

    if (t + 1 < T_STEPS) {
      // drain: reset (issued at loop top, ~a full MFMA+gates ago) and stale
      // prefetches -> near-free; guarantees reset visible before publish
      asm volatile("s_waitcnt vmcnt(0)" ::: "memory");

      // publish h(t+1): ONE fire-and-forget 8B store (the data IS the flag)
      __hip_atomic_store(h64 + (size_t)((t + 1) & 3) * SLOT_U64 + pub_u64,
                         hv.u, __ATOMIC_RELAXED, __HIP_MEMORY_SCOPE_AGENT);

      // speculative load of next step's quarter (slot t+1) -- arrives
      // during xp-MFMA + loop latency; poll above usually 0-1 iterations
      {
        const unsigned long long* hp2 =
            h64 + (size_t)((t + 1) & 3) * SLOT_U64 + con_u64;
        #pragma unroll
        for (int i = 0; i < 4; ++i) {
          const int kc = w * 4 + i;
          lo[i] = __hip_atomic_load(hp2 + kc * 8,     __ATOMIC_RELAXED, __HIP_MEMORY_SCOPE_AGENT);
          hi[i] = __hip_atomic_load(hp2 + kc * 8 + 1, __ATOMIC_RELAXED, __HIP_MEMORY_SCOPE_AGENT);
        }
      }

      // X(t+2) prefetch into buf[t&1] (consumed at step t+1's xp)
      {
        const int tn = (t + 2 < T_STEPS) ? (t + 2) : (T_STEPS - 1);
        const float* xp = Xb + (size_t)tn * DIM + q * 8;
        f32x4* dst = (t & 1) ? xr1 : xr0;
        #pragma unroll
        for (int xc = 0; xc < 4; ++xc) {
          const f32x4* src = (const f32x4*)(xp + xc * 32);
          dst[2 * xc]     = src[0];
          dst[2 * xc + 1] = src[1];
        }
      }

      // xp(t+1) MFMA from buf[(t+1)&1] (loaded last step, long resident)
      #pragma unroll
      for (int mt = 0; mt < 4; ++mt) acc[mt] = (f32x4){0.f, 0.f, 0.f, 0.f};
      const f32x4* xbuf = ((t + 1) & 1) ? xr1 : xr0;
      #pragma unroll
      for (int xc = 0; xc < 4; ++xc) {
        half8 xb = cvt8(xbuf[2 * xc], xbuf[2 * xc + 1]);
        #pragma unroll
        for (int mt = 0; mt < 4; ++mt)
          acc[mt] = __builtin_amdgcn_mfma_f32_16x16x32_f16(wih[xc][mt], xb, acc[mt], 0, 0, 0);
      }
    }
  }

  // epilogue: logits += mean_h * W_lin^T (bias pre-set by init kernel)
  const float inv = 1.0f / (float)T_STEPS;
  float m[4];
  #pragma unroll
  for (int r = 0; r < 4; ++r) m[r] = hsum[r] * inv;
  #pragma unroll
  for (int cls = 0; cls < 10; ++cls) {
    f32x4 wl = *(const f32x4*)(Wlin + (size_t)cls * HID + J + q * 4);
    float p = m[0] * wl[0] + m[1] * wl[1] + m[2] * wl[2] + m[3] * wl[3];
    p += __shfl_xor(p, 16, 64);
    p += __shfl_xor(p, 32, 64);
    if (q == 0) atomicAdd(out + b_my * 10 + cls, p);
  }
}

__global__ void init_out(const float* __restrict__ blin, float* __restrict__ out) {
  const int i = blockIdx.x * blockDim.x + threadIdx.x;
  if (i < BATCH * 10) out[i] = blin[i % 10];
}

extern "C" void kernel_launch(void* const* d_in, const int* in_sizes, int n_in,
                              void* d_out, int out_size, void* d_ws, size_t ws_size,
                              hipStream_t stream) {
  const float* X    = (const float*)d_in[0];
  const float* Wih  = (const float*)d_in[1];
  const float* Whh  = (const float*)d_in[2];
  const float* bih  = (const float*)d_in[3];
  const float* bhh  = (const float*)d_in[4];
  const float* Wlin = (const float*)d_in[5];
  const float* blin = (const float*)d_in[6];
  float* out = (float*)d_out;

  if (ws_size < (size_t)WS_NEEDED) return;

  _Float16* hbuf = (_Float16*)d_ws;

  // 0x7F byte-fill => every 8B chunk reads as SENT (f16 NaN); fresh h has
  // |h|<=1 so no fresh chunk can ever equal SENT.
  hipMemsetAsync(d_ws, 0x7F, WS_NEEDED, stream);
  init_out<<<10, 256, 0, stream>>>(blin, out);
  lstm_persistent<<<128, 256, 0, stream>>>(X, Wih, Whh, bih, bhh, Wlin, out,
                                           hbuf);
}

// Round 5
// 2883.917 us; speedup vs baseline: 1.2950x; 1.2950x over previous
//
#include <hip/hip_runtime.h>
#include <stdint.h>

// LSTM: B=256, T=512, D=128, H=512, C=10
// R14 = synthesis of all proven pieces:
//  - R12 skeleton (16 groups x 8 blocks, LDS-shared h broadcast: each wave
//    loads only its 4-kc quarter = 64B/lane, shares via LDS). [WIN 2832us]
//  - R13's swizzled LDS layout kc*256 + q*64 + col*4 (bank-conflict-free;
//    R13 measured SQ_LDS_BANK_CONFLICT 4.19e7 -> 0). Sentinel machinery is
//    DROPPED for good (two independent regressions: agent stores write
//    through to HBM, doubling WRITE; poll re-reads inflate FETCH).
//  - R9's per-wave release: publish 8B -> s_waitcnt vmcnt(0) (own stores
//    only) -> lane0 stores wave-flag. No release barrier => block's flag
//    isn't gated on its slowest wave.
//  - NEW: narrow poll. Wave w needs kc in [4w,4w+4) = hidden rows owned by
//    blocks 2w,2w+1 = wave-ids 8w..8w+7. It polls ONLY those 8 flags.
//    Safety needs 4 h-slots: me@t passing poll => my 8 producers finished
//    step t-1 => their producers (= ALL 32 waves, since the union of the
//    producer sets of waves 8w..8w+7 covers wid 0..31) finished reading
//    h(t-2). Publishing h(t+1) into slot (t+1)%4 clobbers h(t-3) -- done.
//    Narrow poll lets blocks skew up to ~2 steps, absorbing jitter that a
//    full-group barrier-per-step exposes.
//  - ONE __syncthreads per step (double-buffered LDS; barrier(t) separates
//    read(t-1) from write(t+1) on the same buffer).
//  - X prefetched 2 ahead; issued AFTER the flag store so the pre-flag
//    vmcnt(0) drains only the publish ack.

#define T_STEPS 512
#define BATCH   256
#define DIM     128
#define HID     512
#define NGRP    16
#define BT      16
#define RBUF    4

typedef _Float16 half8 __attribute__((ext_vector_type(8)));
typedef _Float16 half4 __attribute__((ext_vector_type(4)));
typedef float    f32x4 __attribute__((ext_vector_type(4)));
typedef unsigned u32x4 __attribute__((ext_vector_type(4)));

#define SLOT_HALFS (BATCH * HID)
#define SLOT_U64   (SLOT_HALFS / 4)
#define FLG_OFF    (RBUF * SLOT_HALFS * 2)        // 1 MiB of h slots
#define WS_NEEDED  (FLG_OFF + NGRP * 32 * 128)    // + 32 wave-flag lines/group

__device__ __forceinline__ half8 cvt8(f32x4 a, f32x4 b) {
  half8 r;
  r[0]=(_Float16)a[0]; r[1]=(_Float16)a[1]; r[2]=(_Float16)a[2]; r[3]=(_Float16)a[3];
  r[4]=(_Float16)b[0]; r[5]=(_Float16)b[1]; r[6]=(_Float16)b[2]; r[7]=(_Float16)b[3];
  return r;
}
__device__ __forceinline__ half8 load8_cvt(const float* p) {
  const f32x4* q = (const f32x4*)p;
  return cvt8(q[0], q[1]);
}
__device__ __forceinline__ float fsig(float x) {
  return __builtin_amdgcn_rcpf(1.f + __expf(-x));
}
__device__ __forceinline__ float ftanh(float x) {
  return 1.f - 2.f * __builtin_amdgcn_rcpf(1.f + __expf(2.f * x));
}

union h4u { unsigned long long u; half4 h; };
union c16 { unsigned long long u2[2]; u32x4 v; };

__global__ __launch_bounds__(256, 1) void lstm_persistent(
    const float* __restrict__ X,   const float* __restrict__ Wih,
    const float* __restrict__ Whh, const float* __restrict__ bih,
    const float* __restrict__ bhh, const float* __restrict__ Wlin,
    float* __restrict__ out, _Float16* __restrict__ hbuf,
    unsigned* __restrict__ flg)
{
  // double-buffered 16KB h-share; u32 idx = kc*256 + q*64 + col*4
  // (each 32-lane group covers all 32 banks exactly 4x -> conflict-free)
  __shared__ unsigned hsh[2][4096];

  const int tid  = threadIdx.x;
  const int w    = tid >> 6;
  const int lane = tid & 63;
  const int col  = lane & 15;        // batch-within-group; W A-frag row
  const int q    = lane >> 4;        // 0..3
  const int bid  = blockIdx.x;
  const int g    = bid & 15;         // group
  const int blk  = bid >> 4;         // 0..7 within group
  const int J    = blk * 64 + w * 16;   // hidden-unit base owned by this wave
  const int wid  = blk * 4 + w;      // wave id in group, 0..31
  const int b_my = g * BT + col;     // this lane's batch

  // ---- W fragments into registers (once) ----
  half8 whh[16][4];                  // [k-chunk of 32][gate]
  half8 wih[4][4];
  #pragma unroll
  for (int kc = 0; kc < 16; ++kc)
    #pragma unroll
    for (int mt = 0; mt < 4; ++mt) {
      const int row = mt * HID + J + col;
      whh[kc][mt] = load8_cvt(Whh + (size_t)row * HID + kc * 32 + q * 8);
    }
  #pragma unroll
  for (int xc = 0; xc < 4; ++xc)
    #pragma unroll
    for (int mt = 0; mt < 4; ++mt) {
      const int row = mt * HID + J + col;
      wih[xc][mt] = load8_cvt(Wih + (size_t)row * DIM + xc * 32 + q * 8);
    }

  float bias[4][4], c_st[4], hsum[4];
  #pragma unroll
  for (int mt = 0; mt < 4; ++mt)
    #pragma unroll
    for (int r = 0; r < 4; ++r) {
      const int row = mt * HID + J + q * 4 + r;
      bias[mt][r] = bih[row] + bhh[row];
    }
  #pragma unroll
  for (int r = 0; r < 4; ++r) { c_st[r] = 0.f; hsum[r] = 0.f; }

  unsigned* gflg = flg + (size_t)g * 32 * 32;   // 32 wave-flags, 128B apart
  const float* Xb = X + (size_t)b_my * T_STEPS * DIM;
  unsigned long long* h64 = (unsigned long long*)hbuf;
  const size_t pub_u64 = ((size_t)b_my * HID + J + q * 4) >> 2;
  const size_t con_u64 = ((size_t)b_my * HID) >> 2;

  // poll target: wave-ids 8w..8w+7 (producers of this wave's quarter)
  const int  pw   = 8 * w + (lane & 7);
  const bool self = (pw == wid);
  unsigned* pollp = gflg + (size_t)pw * 32;

  // ---- prologue: acc = xp(0); prefetch X(1)->xr1, X(2)->xr0 ----
  f32x4 xr0[8], xr1[8];                // buf[k&1] holds X(k)
  #pragma unroll
  for (int xc = 0; xc < 4; ++xc) {
    const f32x4* p = (const f32x4*)(Xb + xc * 32 + q * 8);
    xr0[2 * xc] = p[0]; xr0[2 * xc + 1] = p[1];
  }
  f32x4 acc[4];
  #pragma unroll
  for (int mt = 0; mt < 4; ++mt) acc[mt] = (f32x4){0.f, 0.f, 0.f, 0.f};
  #pragma unroll
  for (int xc = 0; xc < 4; ++xc) {
    half8 xb = cvt8(xr0[2 * xc], xr0[2 * xc + 1]);
    #pragma unroll
    for (int mt = 0; mt < 4; ++mt)
      acc[mt] = __builtin_amdgcn_mfma_f32_16x16x32_f16(wih[xc][mt], xb, acc[mt], 0, 0, 0);
  }
  #pragma unroll
  for (int xc = 0; xc < 4; ++xc) {
    const f32x4* p1 = (const f32x4*)(Xb + (size_t)1 * DIM + xc * 32 + q * 8);
    const f32x4* p2 = (const f32x4*)(Xb + (size_t)2 * DIM + xc * 32 + q * 8);
    xr1[2 * xc] = p1[0]; xr1[2 * xc + 1] = p1[1];
    xr0[2 * xc] = p2[0]; xr0[2 * xc + 1] = p2[1];
  }

  for (int t = 0; t < T_STEPS; ++t) {
    if (t > 0) {
      // narrow poll: only this wave's 8 quarter-producers (own flag subbed
      // -- our stores were drained before our flag went out)
      for (;;) {
        unsigned v = __hip_atomic_load(pollp, __ATOMIC_RELAXED,
                                       __HIP_MEMORY_SCOPE_AGENT);
        if (self) v = 0xFFFFFFFFu;
        if (__all((int)(v >= (unsigned)t))) break;
      }
      __builtin_amdgcn_sched_barrier(0);  // nothing crosses the spin

      // this wave's quarter of h(t) from slot t%4: kc in [4w,4w+4)
      unsigned long long lo[4], hi[4];
      {
        const unsigned long long* base =
            h64 + (size_t)(t & 3) * SLOT_U64 + con_u64;
        #pragma unroll
        for (int i = 0; i < 4; ++i) {
          const int kc = w * 4 + i;
          lo[i] = __hip_atomic_load(base + kc * 8 + q * 2,     __ATOMIC_RELAXED, __HIP_MEMORY_SCOPE_AGENT);
          hi[i] = __hip_atomic_load(base + kc * 8 + q * 2 + 1, __ATOMIC_RELAXED, __HIP_MEMORY_SCOPE_AGENT);
        }
      }
      // stage to LDS (swizzled, conflict-free), buffer t&1
      #pragma unroll
      for (int i = 0; i < 4; ++i) {
        const int kc = w * 4 + i;
        c16 u; u.u2[0] = lo[i]; u.u2[1] = hi[i];
        *(u32x4*)(&hsh[t & 1][kc * 256 + q * 64 + col * 4]) = u.v;
      }
      __syncthreads();   // the ONE barrier: write->read; also separates
                         // read(t-1) from write(t+1) on the other buffer

      // full h(t) from LDS -> MFMA
      #pragma unroll
      for (int kc = 0; kc < 16; ++kc) {
        const half8 hbv = *(const half8*)(&hsh[t & 1][kc * 256 + q * 64 + col * 4]);
        #pragma unroll
        for (int mt = 0; mt < 4; ++mt)
          acc[mt] = __builtin_amdgcn_mfma_f32_16x16x32_f16(whh[kc][mt], hbv, acc[mt], 0, 0, 0);
      }
    }

    // gates -> c,h ; each lane owns units J+q*4..+3 for batch col
    h4u hv;
    #pragma unroll
    for (int r = 0; r < 4; ++r) {
      const float ig = fsig(acc[0][r] + bias[0][r]);
      const float fg = fsig(acc[1][r] + bias[1][r]);
      const float gg = ftanh(acc[2][r] + bias[2][r]);
      const float og = fsig(acc[3][r] + bias[3][r]);
      const float cc = fg * c_st[r] + ig * gg;
      c_st[r] = cc;
      const float h = og * ftanh(cc);
      hsum[r] += h;
      hv.h[r] = (_Float16)h;
    }

    if (t + 1 < T_STEPS) {
      // publish h(t+1) into slot (t+1)%4 (clobbers h(t-3): safe, see header)
      __hip_atomic_store(h64 + (size_t)((t + 1) & 3) * SLOT_U64 + pub_u64,
                         hv.u, __ATOMIC_RELAXED, __HIP_MEMORY_SCOPE_AGENT);

      // per-wave release: drain OWN stores (publish ack only -- X prefetch
      // from last step is long done), then lane0 flag. No block barrier.
      asm volatile("s_waitcnt vmcnt(0)" ::: "memory");
      if (lane == 0)
        __hip_atomic_store(gflg + (size_t)wid * 32, (unsigned)(t + 1),
                           __ATOMIC_RELAXED, __HIP_MEMORY_SCOPE_AGENT);

      // X(t+2) prefetch into buf[t&1] -- after the flag, so the next drain
      // never waits on HBM; consumed at step t+1's xp
      {
        const int tn = (t + 2 < T_STEPS) ? (t + 2) : (T_STEPS - 1);
        const float* xp = Xb + (size_t)tn * DIM + q * 8;
        f32x4* dst = (t & 1) ? xr1 : xr0;
        #pragma unroll
        for (int xc = 0; xc < 4; ++xc) {
          const f32x4* src = (const f32x4*)(xp + xc * 32);
          dst[2 * xc]     = src[0];
          dst[2 * xc + 1] = src[1];
        }
      }

      // xp(t+1) MFMA from buf[(t+1)&1] (loaded last step, long resident)
      #pragma unroll
      for (int mt = 0; mt < 4; ++mt) acc[mt] = (f32x4){0.f, 0.f, 0.f, 0.f};
      const f32x4* xbuf = ((t + 1) & 1) ? xr1 : xr0;
      #pragma unroll
      for (int xc = 0; xc < 4; ++xc) {
        half8 xb = cvt8(xbuf[2 * xc], xbuf[2 * xc + 1]);
        #pragma unroll
        for (int mt = 0; mt < 4; ++mt)
          acc[mt] = __builtin_amdgcn_mfma_f32_16x16x32_f16(wih[xc][mt], xb, acc[mt], 0, 0, 0);
      }
    }
  }

  // epilogue: logits += mean_h * W_lin^T (bias pre-set by init kernel)
  const float inv = 1.0f / (float)T_STEPS;
  float m[4];
  #pragma unroll
  for (int r = 0; r < 4; ++r) m[r] = hsum[r] * inv;
  #pragma unroll
  for (int cls = 0; cls < 10; ++cls) {
    f32x4 wl = *(const f32x4*)(Wlin + (size_t)cls * HID + J + q * 4);
    float p = m[0] * wl[0] + m[1] * wl[1] + m[2] * wl[2] + m[3] * wl[3];
    p += __shfl_xor(p, 16, 64);
    p += __shfl_xor(p, 32, 64);
    if (q == 0) atomicAdd(out + b_my * 10 + cls, p);
  }
}

__global__ void init_out(const float* __restrict__ blin, float* __restrict__ out) {
  const int i = blockIdx.x * blockDim.x + threadIdx.x;
  if (i < BATCH * 10) out[i] = blin[i % 10];
}

extern "C" void kernel_launch(void* const* d_in, const int* in_sizes, int n_in,
                              void* d_out, int out_size, void* d_ws, size_t ws_size,
                              hipStream_t stream) {
  const float* X    = (const float*)d_in[0];
  const float* Wih  = (const float*)d_in[1];
  const float* Whh  = (const float*)d_in[2];
  const float* bih  = (const float*)d_in[3];
  const float* bhh  = (const float*)d_in[4];
  const float* Wlin = (const float*)d_in[5];
  const float* blin = (const float*)d_in[6];
  float* out = (float*)d_out;

  if (ws_size < (size_t)WS_NEEDED) return;

  _Float16* hbuf = (_Float16*)d_ws;
  unsigned* flg  = (unsigned*)((char*)d_ws + FLG_OFF);

  // only flags need zeroing; hbuf reads are flag-gated
  hipMemsetAsync((char*)d_ws + FLG_OFF, 0, NGRP * 32 * 128, stream);
  init_out<<<10, 256, 0, stream>>>(blin, out);
  lstm_persistent<<<128, 256, 0, stream>>>(X, Wih, Whh, bih, bhh, Wlin, out,
                                           hbuf, flg);
}